// Round 15
// baseline (672.516 us; speedup 1.0000x reference)
//
#include <hip/hip_runtime.h>
#include <hip/hip_bf16.h>

#define T_TOK 2048
#define DDIM  1024
#define NEXP  8
#define FDIM  4096
#define ROWS  (4096 + 256)

typedef __attribute__((ext_vector_type(8))) short bf16x8;
typedef __attribute__((ext_vector_type(4))) float f32x4;

#define SBW(n) ((((n) >> 3) ^ (n)) & 7)

__device__ __forceinline__ unsigned short f2b(float f) {
  union { float f; unsigned u; } v; v.f = f;
  unsigned r = v.u + 0x7FFF + ((v.u >> 16) & 1);  // RNE
  return (unsigned short)(r >> 16);
}
__device__ __forceinline__ float b2f(unsigned short s) {
  union { unsigned u; float f; } v; v.u = ((unsigned)s) << 16;
  return v.f;
}
__device__ __forceinline__ unsigned cvtpk(float lo, float hi) {
  unsigned r;
  asm("v_cvt_pk_bf16_f32 %0, %1, %2" : "=v"(r) : "v"(lo), "v"(hi));
  return r;
}
__device__ __forceinline__ void gl16(const unsigned short* g, unsigned short* l) {
  __builtin_amdgcn_global_load_lds(
      (const __attribute__((address_space(1))) unsigned int*)(const void*)g,
      (__attribute__((address_space(3))) unsigned int*)(void*)l, 16, 0, 0);
}
__device__ __forceinline__ bf16x8 pack8(const float4* br, int c) {
  union { bf16x8 v; unsigned u[4]; } p;
  p.u[0] = cvtpk((&br[0].x)[c], (&br[1].x)[c]);
  p.u[1] = cvtpk((&br[2].x)[c], (&br[3].x)[c]);
  p.u[2] = cvtpk((&br[4].x)[c], (&br[5].x)[c]);
  p.u[3] = cvtpk((&br[6].x)[c], (&br[7].x)[c]);
  return p.v;
}

// counted barrier: keep the 12 newest vmem ops (4 gl16 + 8 B-prefetch) in
// flight; drain older (this tile's A gl16 + last tile's B loads). lgkm0
// publishes ds_writes. (pattern validated R6)
#define BAR_KEEP12()                                              \
  __builtin_amdgcn_sched_barrier(0);                              \
  asm volatile("s_waitcnt vmcnt(12) lgkmcnt(0)" ::: "memory");    \
  __builtin_amdgcn_s_barrier();                                   \
  __builtin_amdgcn_sched_barrier(0)
#define BAR_PLAIN()                                               \
  __builtin_amdgcn_sched_barrier(0);                              \
  __builtin_amdgcn_s_barrier();                                   \
  __builtin_amdgcn_sched_barrier(0)

// ---------------- router ----------------
__global__ void router_kernel(const float* __restrict__ x, const float* __restrict__ Wr,
                              int* __restrict__ cnt, int* __restrict__ tok,
                              float* __restrict__ prb) {
  int t = (blockIdx.x * blockDim.x + threadIdx.x) >> 6;
  int lane = threadIdx.x & 63;
  if (t >= T_TOK) return;
  const float* xr = x + (size_t)t * DDIM;
  float acc[NEXP];
#pragma unroll
  for (int e = 0; e < NEXP; ++e) acc[e] = 0.f;
#pragma unroll
  for (int i = 0; i < 4; ++i) {
    int d0 = lane * 16 + i * 4;
    float4 xv = *reinterpret_cast<const float4*>(xr + d0);
#pragma unroll
    for (int j = 0; j < 4; ++j) {
      float xd = (&xv.x)[j];
      float4 w0 = *reinterpret_cast<const float4*>(Wr + (size_t)(d0 + j) * NEXP);
      float4 w1 = *reinterpret_cast<const float4*>(Wr + (size_t)(d0 + j) * NEXP + 4);
      acc[0] += xd * w0.x; acc[1] += xd * w0.y; acc[2] += xd * w0.z; acc[3] += xd * w0.w;
      acc[4] += xd * w1.x; acc[5] += xd * w1.y; acc[6] += xd * w1.z; acc[7] += xd * w1.w;
    }
  }
#pragma unroll
  for (int off = 32; off >= 1; off >>= 1)
#pragma unroll
    for (int e = 0; e < NEXP; ++e) acc[e] += __shfl_down(acc[e], off);
  if (lane == 0) {
    float v0 = -1e30f, v1 = -1e30f; int i0 = 0, i1 = 0;
#pragma unroll
    for (int e = 0; e < NEXP; ++e) {
      float v = acc[e];
      if (v > v0)      { v1 = v0; i1 = i0; v0 = v; i0 = e; }
      else if (v > v1) { v1 = v; i1 = e; }
    }
    float e1 = __expf(v1 - v0);
    float p0 = 1.f / (1.f + e1);
    float p1 = e1 * p0;
    int s0 = atomicAdd(&cnt[i0], 1);
    tok[i0 * T_TOK + s0] = t; prb[i0 * T_TOK + s0] = p0;
    int s1 = atomicAdd(&cnt[i1], 1);
    tok[i1 * T_TOK + s1] = t; prb[i1 * T_TOK + s1] = p1;
  }
}

// ---------------- gather+cvt: xg[off_e + s] = bf16(x[tok[e][s]]) ------------
__global__ void gather_x_kernel(const float* __restrict__ x, const int* __restrict__ cnt,
                                const int* __restrict__ tok, unsigned short* __restrict__ xg) {
  int gs = blockIdx.x * 4 + (threadIdx.x >> 6);   // global slot [0, 4096)
  int lane = threadIdx.x & 63;
  int s = gs, e = 0;
#pragma unroll
  for (int i = 0; i < NEXP - 1; ++i) {
    int c = cnt[i];
    bool go = (e == i) && (s >= c);
    if (go) { s -= c; e = i + 1; }
  }
  int tk = tok[e * T_TOK + s];
  const float* src = x + (size_t)tk * DDIM;
  unsigned short* dst = xg + (size_t)gs * DDIM;
#pragma unroll
  for (int it = 0; it < 4; ++it) {
    float4 v = *reinterpret_cast<const float4*>(src + it * 256 + lane * 4);
    uint2 p;
    p.x = cvtpk(v.x, v.y);
    p.y = cvtpk(v.z, v.w);
    *reinterpret_cast<uint2*>(dst + it * 256 + lane * 4) = p;
  }
}

// ======== fused GEMM1: act = silu(xg@W1) * (xg@W3) ========
// Depth-2 B prefetch (brA/brB), dbuf sA, counted barriers. 48 KB LDS, 3/CU.
__global__ __launch_bounds__(256, 3)
void gemm1ab_kernel(const unsigned short* __restrict__ xg,
                    const float* __restrict__ W1, const float* __restrict__ W3,
                    const int* __restrict__ cnt,
                    unsigned short* __restrict__ act) {
  const int e = blockIdx.z;
  const int cn = cnt[e];
  const int r0 = blockIdx.y * 128;
  if (r0 >= cn) return;
  const int n0 = blockIdx.x * 64;
  int off = 0;
#pragma unroll
  for (int i = 0; i < NEXP; ++i) off += (i < e) ? cnt[i] : 0;

  __shared__ __align__(16) unsigned short sA[2][128 * 64];   // 32 KB
  __shared__ __align__(16) unsigned short sB1[64 * 64];      // 8 KB
  __shared__ __align__(16) unsigned short sB3[64 * 64];      // 8 KB

  const int tid = threadIdx.x;
  const int lane = tid & 63;
  const int wid = tid >> 6;
  const int wm = wid >> 1, wn = wid & 1;

  // A staging: dense compacted rows (pre-swizzled per-lane source)
  const unsigned short* asrc[4];
#pragma unroll
  for (int i = 0; i < 4; ++i) {
    int row = (4 * wid + i) * 8 + (lane >> 3);
    int sl = (lane & 7) ^ (row & 7);
    asrc[i] = xg + (size_t)(off + r0 + row) * DDIM + sl * 8;
  }

  // B staging: tid<128 stages W1, tid>=128 stages W3; thread owns 8k x 4n.
  const int lt = tid & 127;
  const int ko = lt >> 4;
  const int nc = (lt & 15) * 4;
  const float* bp = ((tid < 128) ? W1 : W3) + ((size_t)e * DDIM + 8 * ko) * FDIM + n0 + nc;
  unsigned short* wb = (tid < 128) ? sB1 : sB3;
  int woff[4];
#pragma unroll
  for (int c = 0; c < 4; ++c) woff[c] = (nc + c) * 64 + ((ko ^ SBW(nc + c)) * 8);

  float4 brA[8], brB[8];
#define LOADB1(BR, K0)                                                          \
  _Pragma("unroll") for (int r = 0; r < 8; ++r)                                 \
      BR[r] = *reinterpret_cast<const float4*>(bp + (size_t)((K0) + r) * FDIM);
#define WRITEB1(BR)                                                             \
  _Pragma("unroll") for (int c = 0; c < 4; ++c)                                 \
      *reinterpret_cast<bf16x8*>(wb + woff[c]) = pack8(BR, c);
#define STAGEA1(K0, BUF)                                                        \
  _Pragma("unroll") for (int i = 0; i < 4; ++i)                                 \
      gl16(asrc[i] + (K0), &sA[BUF][(4 * wid + i) * 512]);

  f32x4 ah[4][2], ag[4][2];
#pragma unroll
  for (int m = 0; m < 4; ++m)
#pragma unroll
    for (int n = 0; n < 2; ++n) { ah[m][n] = (f32x4){0,0,0,0}; ag[m][n] = (f32x4){0,0,0,0}; }

#define MFMA1(CUR)                                                              \
  _Pragma("unroll") for (int kk = 0; kk < 2; ++kk) {                            \
    int kc8 = kk * 4 + (lane >> 4);                                             \
    bf16x8 a[4], b1[2], b3[2];                                                  \
    _Pragma("unroll") for (int m = 0; m < 4; ++m) {                             \
      int row = wm * 64 + m * 16 + (lane & 15);                                 \
      a[m] = *reinterpret_cast<const bf16x8*>(&sA[CUR][row * 64 + ((kc8 ^ (row & 7)) * 8)]); \
    }                                                                           \
    _Pragma("unroll") for (int n = 0; n < 2; ++n) {                             \
      int rowb = wn * 32 + n * 16 + (lane & 15);                                \
      int offb = rowb * 64 + ((kc8 ^ SBW(rowb)) * 8);                           \
      b1[n] = *reinterpret_cast<const bf16x8*>(&sB1[offb]);                     \
      b3[n] = *reinterpret_cast<const bf16x8*>(&sB3[offb]);                     \
    }                                                                           \
    _Pragma("unroll") for (int m = 0; m < 4; ++m)                               \
      _Pragma("unroll") for (int n = 0; n < 2; ++n) {                           \
        ah[m][n] = __builtin_amdgcn_mfma_f32_16x16x32_bf16(a[m], b1[n], ah[m][n], 0, 0, 0); \
        ag[m][n] = __builtin_amdgcn_mfma_f32_16x16x32_bf16(a[m], b3[n], ag[m][n], 0, 0, 0); \
      }                                                                         \
  }

#define HALF1(K0, BR, CUR)                                                      \
  WRITEB1(BR);                          /* waits BR loads (2 halves old) */     \
  STAGEA1(((K0) + 64) & (DDIM - 1), (CUR) ^ 1);  /* gl16 prefetch next A */     \
  LOADB1(BR, ((K0) + 128) & (DDIM - 1));         /* refill freed buffer  */     \
  BAR_KEEP12();                                                                 \
  __builtin_amdgcn_s_setprio(1);                                                \
  MFMA1(CUR);                                                                   \
  __builtin_amdgcn_s_setprio(0);                                                \
  BAR_PLAIN();

  // prologue: brA<-k0, brB<-k64, sA[0]<-k0
  LOADB1(brA, 0);
  LOADB1(brB, 64);
  STAGEA1(0, 0);

  for (int k0 = 0; k0 < DDIM; k0 += 128) {
    HALF1(k0, brA, 0);
    HALF1(k0 + 64, brB, 1);
  }
#undef HALF1
#undef MFMA1
#undef LOADB1
#undef WRITEB1
#undef STAGEA1

  // epilogue: act = silu(h) * g
#pragma unroll
  for (int m = 0; m < 4; ++m)
#pragma unroll
    for (int j = 0; j < 4; ++j) {
      int rloc = wm * 64 + m * 16 + (lane >> 4) * 4 + j;
      int s = r0 + rloc;
      if (s < cn) {
        unsigned short* orow = act + (size_t)(off + s) * FDIM + n0 + wn * 32 + (lane & 15);
#pragma unroll
        for (int n = 0; n < 2; ++n) {
          float hv = ah[m][n][j];
          float gv = ag[m][n][j];
          float sg = hv / (1.f + __expf(-hv));
          orow[n * 16] = f2b(sg * gv);
        }
      }
    }
}

// ======== GEMM2: out += p * act @ W2 (split-K=2, atomics) ========
// Same depth-2 pipeline. Tile 128m x 128n, 48 KB LDS, 3/CU.
__global__ __launch_bounds__(256, 3)
void gemm2d_kernel(const unsigned short* __restrict__ act, const float* __restrict__ W2,
                   const int* __restrict__ cnt, const int* __restrict__ tok,
                   const float* __restrict__ prb, float* __restrict__ out) {
  const int e = blockIdx.z >> 1;
  const int sp = blockIdx.z & 1;
  const int cn = cnt[e];
  const int r0 = blockIdx.y * 128;
  if (r0 >= cn) return;
  const int n0 = blockIdx.x * 128;
  const int kbase = sp * (FDIM / 2);
  int off = 0;
#pragma unroll
  for (int i = 0; i < NEXP; ++i) off += (i < e) ? cnt[i] : 0;

  __shared__ __align__(16) unsigned short sA[2][128 * 64];   // 32 KB
  __shared__ __align__(16) unsigned short sB[128 * 64];      // 16 KB

  const int tid = threadIdx.x;
  const int lane = tid & 63;
  const int wid = tid >> 6;
  const int wm = wid >> 1, wn = wid & 1;

  const unsigned short* asrc[4];
#pragma unroll
  for (int i = 0; i < 4; ++i) {
    int row = (4 * wid + i) * 8 + (lane >> 3);
    int sl = (lane & 7) ^ (row & 7);
    asrc[i] = act + (size_t)(off + r0 + row) * FDIM + kbase + sl * 8;
  }

  const int ko = tid >> 5;          // 0..7
  const int nc = (tid & 31) * 4;    // 0..124
  const float* bp = W2 + ((size_t)e * FDIM + kbase + 8 * ko) * DDIM + n0 + nc;
  int woff[4];
#pragma unroll
  for (int c = 0; c < 4; ++c) woff[c] = (nc + c) * 64 + ((ko ^ SBW(nc + c)) * 8);

  float4 brA[8], brB[8];
#define LOADB2(BR, K0)                                                          \
  _Pragma("unroll") for (int r = 0; r < 8; ++r)                                 \
      BR[r] = *reinterpret_cast<const float4*>(bp + (size_t)((K0) + r) * DDIM);
#define WRITEB2(BR)                                                             \
  _Pragma("unroll") for (int c = 0; c < 4; ++c)                                 \
      *reinterpret_cast<bf16x8*>(&sB[woff[c]]) = pack8(BR, c);
#define STAGEA2(K0, BUF)                                                        \
  _Pragma("unroll") for (int i = 0; i < 4; ++i)                                 \
      gl16(asrc[i] + (K0), &sA[BUF][(4 * wid + i) * 512]);

  f32x4 acc[4][4];
#pragma unroll
  for (int m = 0; m < 4; ++m)
#pragma unroll
    for (int n = 0; n < 4; ++n) acc[m][n] = (f32x4){0,0,0,0};

#define MFMA2(CUR)                                                              \
  _Pragma("unroll") for (int kk = 0; kk < 2; ++kk) {                            \
    int kc8 = kk * 4 + (lane >> 4);                                             \
    bf16x8 a[4], b[4];                                                          \
    _Pragma("unroll") for (int m = 0; m < 4; ++m) {                             \
      int row = wm * 64 + m * 16 + (lane & 15);                                 \
      a[m] = *reinterpret_cast<const bf16x8*>(&sA[CUR][row * 64 + ((kc8 ^ (row & 7)) * 8)]); \
    }                                                                           \
    _Pragma("unroll") for (int n = 0; n < 4; ++n) {                             \
      int col = wn * 64 + n * 16 + (lane & 15);                                 \
      b[n] = *reinterpret_cast<const bf16x8*>(&sB[col * 64 + ((kc8 ^ SBW(col)) * 8)]); \
    }                                                                           \
    _Pragma("unroll") for (int m = 0; m < 4; ++m)                               \
      _Pragma("unroll") for (int n = 0; n < 4; ++n)                             \
        acc[m][n] = __builtin_amdgcn_mfma_f32_16x16x32_bf16(a[m], b[n], acc[m][n], 0, 0, 0); \
  }

#define HALF2(K0, BR, CUR)                                                      \
  WRITEB2(BR);                                                                  \
  STAGEA2(((K0) + 64) & (FDIM / 2 - 1), (CUR) ^ 1);                             \
  LOADB2(BR, ((K0) + 128) & (FDIM / 2 - 1));                                    \
  BAR_KEEP12();                                                                 \
  __builtin_amdgcn_s_setprio(1);                                                \
  MFMA2(CUR);                                                                   \
  __builtin_amdgcn_s_setprio(0);                                                \
  BAR_PLAIN();

  LOADB2(brA, 0);
  LOADB2(brB, 64);
  STAGEA2(0, 0);

  for (int k0 = 0; k0 < FDIM / 2; k0 += 128) {
    HALF2(k0, brA, 0);
    HALF2(k0 + 64, brB, 1);
  }
#undef HALF2
#undef MFMA2
#undef LOADB2
#undef WRITEB2
#undef STAGEA2

#pragma unroll
  for (int m = 0; m < 4; ++m)
#pragma unroll
    for (int j = 0; j < 4; ++j) {
      int rloc = wm * 64 + m * 16 + (lane >> 4) * 4 + j;
      int s = r0 + rloc;
      if (s < cn) {
        int tkn = tok[e * T_TOK + s];
        float p = prb[e * T_TOK + s];
        float* orow = out + (size_t)tkn * DDIM + n0 + wn * 64 + (lane & 15);
#pragma unroll
        for (int n = 0; n < 4; ++n) atomicAdd(&orow[n * 16], p * acc[m][n][j]);
      }
    }
}

// ============================================================================
extern "C" void kernel_launch(void* const* d_in, const int* in_sizes, int n_in,
                              void* d_out, int out_size, void* d_ws, size_t ws_size,
                              hipStream_t stream) {
  const float* x  = (const float*)d_in[0];
  const float* Wr = (const float*)d_in[1];
  const float* W1 = (const float*)d_in[2];
  const float* W2 = (const float*)d_in[3];
  const float* W3 = (const float*)d_in[4];
  float* out = (float*)d_out;

  char* ws = (char*)d_ws;
  int*   cnt = (int*)ws;                      // 32 B
  int*   tok = (int*)(ws + 1024);             // 64 KB
  float* prb = (float*)(ws + 1024 + 65536);   // 64 KB
  unsigned short* xg  = (unsigned short*)(ws + 256 * 1024);   // ROWS x DDIM bf16
  unsigned short* act = xg + (size_t)ROWS * DDIM;             // ROWS x FDIM bf16

  hipMemsetAsync(cnt, 0, NEXP * sizeof(int), stream);
  hipMemsetAsync(d_out, 0, (size_t)out_size * sizeof(float), stream);

  router_kernel<<<T_TOK / 4, 256, 0, stream>>>(x, Wr, cnt, tok, prb);
  gather_x_kernel<<<(2 * T_TOK) / 4, 256, 0, stream>>>(x, cnt, tok, xg);
  gemm1ab_kernel<<<dim3(FDIM / 64, 16, NEXP), 256, 0, stream>>>(xg, W1, W3, cnt, act);
  gemm2d_kernel<<<dim3(DDIM / 128, 16, NEXP * 2), 256, 0, stream>>>(act, W2, cnt, tok, prb, out);
}

// Round 16
// 348.812 us; speedup vs baseline: 1.9280x; 1.9280x over previous
//
#include <hip/hip_runtime.h>
#include <hip/hip_bf16.h>

#define T_TOK 2048
#define DDIM  1024
#define NEXP  8
#define FDIM  4096
#define ROWS  (4096 + 256)

typedef __attribute__((ext_vector_type(8))) short bf16x8;
typedef __attribute__((ext_vector_type(4))) float f32x4;

#define SBW(n) ((((n) >> 3) ^ (n)) & 7)

__device__ __forceinline__ unsigned short f2b(float f) {
  union { float f; unsigned u; } v; v.f = f;
  unsigned r = v.u + 0x7FFF + ((v.u >> 16) & 1);  // RNE
  return (unsigned short)(r >> 16);
}
__device__ __forceinline__ float b2f(unsigned short s) {
  union { unsigned u; float f; } v; v.u = ((unsigned)s) << 16;
  return v.f;
}
__device__ __forceinline__ unsigned cvtpk(float lo, float hi) {
  unsigned r;
  asm("v_cvt_pk_bf16_f32 %0, %1, %2" : "=v"(r) : "v"(lo), "v"(hi));
  return r;
}
__device__ __forceinline__ void gl16(const unsigned short* g, unsigned short* l) {
  __builtin_amdgcn_global_load_lds(
      (const __attribute__((address_space(1))) unsigned int*)(const void*)g,
      (__attribute__((address_space(3))) unsigned int*)(void*)l, 16, 0, 0);
}
__device__ __forceinline__ bf16x8 pack8(const float4* br, int c) {
  union { bf16x8 v; unsigned u[4]; } p;
  p.u[0] = cvtpk((&br[0].x)[c], (&br[1].x)[c]);
  p.u[1] = cvtpk((&br[2].x)[c], (&br[3].x)[c]);
  p.u[2] = cvtpk((&br[4].x)[c], (&br[5].x)[c]);
  p.u[3] = cvtpk((&br[6].x)[c], (&br[7].x)[c]);
  return p.v;
}

// ---------------- router ----------------
__global__ void router_kernel(const float* __restrict__ x, const float* __restrict__ Wr,
                              int* __restrict__ cnt, int* __restrict__ tok,
                              float* __restrict__ prb) {
  int t = (blockIdx.x * blockDim.x + threadIdx.x) >> 6;
  int lane = threadIdx.x & 63;
  if (t >= T_TOK) return;
  const float* xr = x + (size_t)t * DDIM;
  float acc[NEXP];
#pragma unroll
  for (int e = 0; e < NEXP; ++e) acc[e] = 0.f;
#pragma unroll
  for (int i = 0; i < 4; ++i) {
    int d0 = lane * 16 + i * 4;
    float4 xv = *reinterpret_cast<const float4*>(xr + d0);
#pragma unroll
    for (int j = 0; j < 4; ++j) {
      float xd = (&xv.x)[j];
      float4 w0 = *reinterpret_cast<const float4*>(Wr + (size_t)(d0 + j) * NEXP);
      float4 w1 = *reinterpret_cast<const float4*>(Wr + (size_t)(d0 + j) * NEXP + 4);
      acc[0] += xd * w0.x; acc[1] += xd * w0.y; acc[2] += xd * w0.z; acc[3] += xd * w0.w;
      acc[4] += xd * w1.x; acc[5] += xd * w1.y; acc[6] += xd * w1.z; acc[7] += xd * w1.w;
    }
  }
#pragma unroll
  for (int off = 32; off >= 1; off >>= 1)
#pragma unroll
    for (int e = 0; e < NEXP; ++e) acc[e] += __shfl_down(acc[e], off);
  if (lane == 0) {
    float v0 = -1e30f, v1 = -1e30f; int i0 = 0, i1 = 0;
#pragma unroll
    for (int e = 0; e < NEXP; ++e) {
      float v = acc[e];
      if (v > v0)      { v1 = v0; i1 = i0; v0 = v; i0 = e; }
      else if (v > v1) { v1 = v; i1 = e; }
    }
    float e1 = __expf(v1 - v0);
    float p0 = 1.f / (1.f + e1);
    float p1 = e1 * p0;
    int s0 = atomicAdd(&cnt[i0], 1);
    tok[i0 * T_TOK + s0] = t; prb[i0 * T_TOK + s0] = p0;
    int s1 = atomicAdd(&cnt[i1], 1);
    tok[i1 * T_TOK + s1] = t; prb[i1 * T_TOK + s1] = p1;
  }
}

// ---------------- gather+cvt: xg[off_e + s] = bf16(x[tok[e][s]]) ------------
__global__ void gather_x_kernel(const float* __restrict__ x, const int* __restrict__ cnt,
                                const int* __restrict__ tok, unsigned short* __restrict__ xg) {
  int gs = blockIdx.x * 4 + (threadIdx.x >> 6);   // global slot [0, 4096)
  int lane = threadIdx.x & 63;
  int s = gs, e = 0;
#pragma unroll
  for (int i = 0; i < NEXP - 1; ++i) {
    int c = cnt[i];
    bool go = (e == i) && (s >= c);
    if (go) { s -= c; e = i + 1; }
  }
  int tk = tok[e * T_TOK + s];
  const float* src = x + (size_t)tk * DDIM;
  unsigned short* dst = xg + (size_t)gs * DDIM;
#pragma unroll
  for (int it = 0; it < 4; ++it) {
    float4 v = *reinterpret_cast<const float4*>(src + it * 256 + lane * 4);
    uint2 p;
    p.x = cvtpk(v.x, v.y);
    p.y = cvtpk(v.z, v.w);
    *reinterpret_cast<uint2*>(dst + it * 256 + lane * 4) = p;
  }
}

// ======== fused GEMM1: act = silu(xg@W1) * (xg@W3) ========
// BM=256, BN=64 (dual). 512 threads: waves 0-1 stage W1, 2-3 stage W3,
// 4-7 stage A (gl16). All 8 waves compute 32 rows x 64 cols (h+g).
// R14 two-barrier skeleton; W re-reads halved vs BM=128.
__global__ __launch_bounds__(512, 2)
void gemm1ab_kernel(const unsigned short* __restrict__ xg,
                    const float* __restrict__ W1, const float* __restrict__ W3,
                    const int* __restrict__ cnt,
                    unsigned short* __restrict__ act) {
  const int e = blockIdx.z;
  const int cn = cnt[e];
  const int r0 = blockIdx.y * 256;
  if (r0 >= cn) return;
  const int n0 = blockIdx.x * 64;
  int off = 0;
#pragma unroll
  for (int i = 0; i < NEXP; ++i) off += (i < e) ? cnt[i] : 0;

  __shared__ __align__(16) unsigned short sA[256 * 64];      // 32 KB
  __shared__ __align__(16) unsigned short sB1[64 * 64];      // 8 KB
  __shared__ __align__(16) unsigned short sB3[64 * 64];      // 8 KB

  const int tid = threadIdx.x;
  const int lane = tid & 63;
  const int w = tid >> 6;            // 0..7

  // ---- B staging (waves 0-3): thread owns 8k x 4n, b128 writes ----
  const int lt = tid & 127;
  const int ko = lt >> 4;            // 0..7
  const int nc = (lt & 15) * 4;      // 0..60
  const float* bp = ((tid & 128) ? W3 : W1) + ((size_t)e * DDIM + 8 * ko) * FDIM + n0 + nc;
  unsigned short* wb = (tid & 128) ? sB3 : sB1;
  int woff[4];
#pragma unroll
  for (int c = 0; c < 4; ++c) woff[c] = (nc + c) * 64 + ((ko ^ SBW(nc + c)) * 8);

  // ---- A staging (waves 4-7): 8 gl16/thread covering 256 rows ----
  const unsigned short* asrc[8];
  {
    int w4 = (tid >> 6) & 3;         // 0..3 for waves 4-7
#pragma unroll
    for (int i = 0; i < 8; ++i) {
      int row = (w4 * 8 + i) * 8 + (lane >> 3);
      int sl = (lane & 7) ^ (row & 7);
      asrc[i] = xg + (size_t)(off + r0 + row) * DDIM + sl * 8;
    }
  }

  float4 br[8];
#define LOADB1(K0)                                                              \
  _Pragma("unroll") for (int r = 0; r < 8; ++r)                                 \
      br[r] = *reinterpret_cast<const float4*>(bp + (size_t)((K0) + r) * FDIM);
#define WRITEB1()                                                               \
  _Pragma("unroll") for (int c = 0; c < 4; ++c)                                 \
      *reinterpret_cast<bf16x8*>(wb + woff[c]) = pack8(br, c);
#define STAGEA1(K0)                                                             \
  {                                                                             \
    int w4s = (tid >> 6) & 3;                                                   \
    _Pragma("unroll") for (int i = 0; i < 8; ++i)                               \
        gl16(asrc[i] + (K0), &sA[(w4s * 8 + i) * 512]);                         \
  }

  f32x4 ah[2][4], ag[2][4];
#pragma unroll
  for (int m = 0; m < 2; ++m)
#pragma unroll
    for (int n = 0; n < 4; ++n) { ah[m][n] = (f32x4){0,0,0,0}; ag[m][n] = (f32x4){0,0,0,0}; }

  if (w < 4) LOADB1(0);

  for (int k0 = 0; k0 < DDIM; k0 += 64) {
    if (w < 4) { WRITEB1(); } else { STAGEA1(k0); }
    __syncthreads();                       // drain gl16 + ds_writes
    if (w < 4 && k0 + 64 < DDIM) LOADB1(k0 + 64);   // prefetch under MFMA
#pragma unroll
    for (int kk = 0; kk < 2; ++kk) {
      int kc8 = kk * 4 + (lane >> 4);
      bf16x8 a[2], b1[4], b3[4];
#pragma unroll
      for (int m = 0; m < 2; ++m) {
        int row = w * 32 + m * 16 + (lane & 15);
        a[m] = *reinterpret_cast<const bf16x8*>(&sA[row * 64 + ((kc8 ^ (row & 7)) * 8)]);
      }
#pragma unroll
      for (int n = 0; n < 4; ++n) {
        int rowb = n * 16 + (lane & 15);
        int offb = rowb * 64 + ((kc8 ^ SBW(rowb)) * 8);
        b1[n] = *reinterpret_cast<const bf16x8*>(&sB1[offb]);
        b3[n] = *reinterpret_cast<const bf16x8*>(&sB3[offb]);
      }
#pragma unroll
      for (int m = 0; m < 2; ++m)
#pragma unroll
        for (int n = 0; n < 4; ++n) {
          ah[m][n] = __builtin_amdgcn_mfma_f32_16x16x32_bf16(a[m], b1[n], ah[m][n], 0, 0, 0);
          ag[m][n] = __builtin_amdgcn_mfma_f32_16x16x32_bf16(a[m], b3[n], ag[m][n], 0, 0, 0);
        }
    }
    __syncthreads();                       // readers done before next writes
  }

  // epilogue: act = silu(h) * g
#pragma unroll
  for (int m = 0; m < 2; ++m)
#pragma unroll
    for (int j = 0; j < 4; ++j) {
      int rloc = w * 32 + m * 16 + (lane >> 4) * 4 + j;
      int s = r0 + rloc;
      if (s < cn) {
        unsigned short* orow = act + (size_t)(off + s) * FDIM + n0 + (lane & 15);
#pragma unroll
        for (int n = 0; n < 4; ++n) {
          float hv = ah[m][n][j];
          float gv = ag[m][n][j];
          float sg = hv / (1.f + __expf(-hv));
          orow[n * 16] = f2b(sg * gv);
        }
      }
    }
}

// ======== GEMM2: out += p * act @ W2 (split-K=4, atomics) ========
// BM=256, BN=128, 512 threads, same wave-role split.
__global__ __launch_bounds__(512, 2)
void gemm2d_kernel(const unsigned short* __restrict__ act, const float* __restrict__ W2,
                   const int* __restrict__ cnt, const int* __restrict__ tok,
                   const float* __restrict__ prb, float* __restrict__ out) {
  const int e = blockIdx.z >> 2;
  const int sp = blockIdx.z & 3;
  const int cn = cnt[e];
  const int r0 = blockIdx.y * 256;
  if (r0 >= cn) return;
  const int n0 = blockIdx.x * 128;
  const int kbase = sp * (FDIM / 4);
  int off = 0;
#pragma unroll
  for (int i = 0; i < NEXP; ++i) off += (i < e) ? cnt[i] : 0;

  __shared__ __align__(16) unsigned short sA[256 * 64];      // 32 KB
  __shared__ __align__(16) unsigned short sB[128 * 64];      // 16 KB

  const int tid = threadIdx.x;
  const int lane = tid & 63;
  const int w = tid >> 6;

  // B staging (waves 0-3, 256 threads): thread owns 8k x 4n of 64k x 128n
  const int lt = tid & 255;
  const int ko = lt >> 5;            // 0..7
  const int nc = (lt & 31) * 4;      // 0..124
  const float* bp = W2 + ((size_t)e * FDIM + kbase + 8 * ko) * DDIM + n0 + nc;
  int woff[4];
#pragma unroll
  for (int c = 0; c < 4; ++c) woff[c] = (nc + c) * 64 + ((ko ^ SBW(nc + c)) * 8);

  // A staging (waves 4-7)
  const unsigned short* asrc[8];
  {
    int w4 = (tid >> 6) & 3;
#pragma unroll
    for (int i = 0; i < 8; ++i) {
      int row = (w4 * 8 + i) * 8 + (lane >> 3);
      int sl = (lane & 7) ^ (row & 7);
      asrc[i] = act + (size_t)(off + r0 + row) * FDIM + kbase + sl * 8;
    }
  }

  float4 br[8];
#define LOADB2(K0)                                                              \
  _Pragma("unroll") for (int r = 0; r < 8; ++r)                                 \
      br[r] = *reinterpret_cast<const float4*>(bp + (size_t)((K0) + r) * DDIM);
#define WRITEB2()                                                               \
  _Pragma("unroll") for (int c = 0; c < 4; ++c)                                 \
      *reinterpret_cast<bf16x8*>(&sB[woff[c]]) = pack8(br, c);
#define STAGEA2(K0)                                                             \
  {                                                                             \
    int w4s = (tid >> 6) & 3;                                                   \
    _Pragma("unroll") for (int i = 0; i < 8; ++i)                               \
        gl16(asrc[i] + (K0), &sA[(w4s * 8 + i) * 512]);                         \
  }

  f32x4 acc[2][8];
#pragma unroll
  for (int m = 0; m < 2; ++m)
#pragma unroll
    for (int n = 0; n < 8; ++n) acc[m][n] = (f32x4){0,0,0,0};

  if (w < 4) LOADB2(0);

  for (int k0 = 0; k0 < FDIM / 4; k0 += 64) {
    if (w < 4) { WRITEB2(); } else { STAGEA2(k0); }
    __syncthreads();
    if (w < 4 && k0 + 64 < FDIM / 4) LOADB2(k0 + 64);
#pragma unroll
    for (int kk = 0; kk < 2; ++kk) {
      int kc8 = kk * 4 + (lane >> 4);
      bf16x8 a[2], b[8];
#pragma unroll
      for (int m = 0; m < 2; ++m) {
        int row = w * 32 + m * 16 + (lane & 15);
        a[m] = *reinterpret_cast<const bf16x8*>(&sA[row * 64 + ((kc8 ^ (row & 7)) * 8)]);
      }
#pragma unroll
      for (int n = 0; n < 8; ++n) {
        int col = n * 16 + (lane & 15);
        b[n] = *reinterpret_cast<const bf16x8*>(&sB[col * 64 + ((kc8 ^ SBW(col)) * 8)]);
      }
#pragma unroll
      for (int m = 0; m < 2; ++m)
#pragma unroll
        for (int n = 0; n < 8; ++n)
          acc[m][n] = __builtin_amdgcn_mfma_f32_16x16x32_bf16(a[m], b[n], acc[m][n], 0, 0, 0);
    }
    __syncthreads();
  }

#pragma unroll
  for (int m = 0; m < 2; ++m)
#pragma unroll
    for (int j = 0; j < 4; ++j) {
      int rloc = w * 32 + m * 16 + (lane >> 4) * 4 + j;
      int s = r0 + rloc;
      if (s < cn) {
        int tkn = tok[e * T_TOK + s];
        float p = prb[e * T_TOK + s];
        float* orow = out + (size_t)tkn * DDIM + n0 + (lane & 15);
#pragma unroll
        for (int n = 0; n < 8; ++n) atomicAdd(&orow[n * 16], p * acc[m][n][j]);
      }
    }
}

// ============================================================================
extern "C" void kernel_launch(void* const* d_in, const int* in_sizes, int n_in,
                              void* d_out, int out_size, void* d_ws, size_t ws_size,
                              hipStream_t stream) {
  const float* x  = (const float*)d_in[0];
  const float* Wr = (const float*)d_in[1];
  const float* W1 = (const float*)d_in[2];
  const float* W2 = (const float*)d_in[3];
  const float* W3 = (const float*)d_in[4];
  float* out = (float*)d_out;

  char* ws = (char*)d_ws;
  int*   cnt = (int*)ws;                      // 32 B
  int*   tok = (int*)(ws + 1024);             // 64 KB
  float* prb = (float*)(ws + 1024 + 65536);   // 64 KB
  unsigned short* xg  = (unsigned short*)(ws + 256 * 1024);   // ROWS x DDIM bf16
  unsigned short* act = xg + (size_t)ROWS * DDIM;             // ROWS x FDIM bf16

  hipMemsetAsync(cnt, 0, NEXP * sizeof(int), stream);
  hipMemsetAsync(d_out, 0, (size_t)out_size * sizeof(float), stream);

  router_kernel<<<T_TOK / 4, 256, 0, stream>>>(x, Wr, cnt, tok, prb);
  gather_x_kernel<<<(2 * T_TOK) / 4, 256, 0, stream>>>(x, cnt, tok, xg);
  gemm1ab_kernel<<<dim3(FDIM / 64, 8, NEXP), 512, 0, stream>>>(xg, W1, W3, cnt, act);
  gemm2d_kernel<<<dim3(DDIM / 128, 8, NEXP * 4), 512, 0, stream>>>(act, W2, cnt, tok, prb, out);
}

// Round 17
// 302.870 us; speedup vs baseline: 2.2205x; 1.1517x over previous
//
#include <hip/hip_runtime.h>
#include <hip/hip_bf16.h>

#define T_TOK 2048
#define DDIM  1024
#define NEXP  8
#define FDIM  4096
#define ROWS  (4096 + 256)

typedef __attribute__((ext_vector_type(8))) short bf16x8;
typedef __attribute__((ext_vector_type(4))) float f32x4;
typedef __attribute__((ext_vector_type(16))) float f32x16;

#define SBW(n) ((((n) >> 3) ^ (n)) & 7)

__device__ __forceinline__ unsigned short f2b(float f) {
  union { float f; unsigned u; } v; v.f = f;
  unsigned r = v.u + 0x7FFF + ((v.u >> 16) & 1);  // RNE
  return (unsigned short)(r >> 16);
}
__device__ __forceinline__ float b2f(unsigned short s) {
  union { unsigned u; float f; } v; v.u = ((unsigned)s) << 16;
  return v.f;
}
__device__ __forceinline__ unsigned cvtpk(float lo, float hi) {
  unsigned r;
  asm("v_cvt_pk_bf16_f32 %0, %1, %2" : "=v"(r) : "v"(lo), "v"(hi));
  return r;
}
__device__ __forceinline__ void gl16(const unsigned short* g, unsigned short* l) {
  __builtin_amdgcn_global_load_lds(
      (const __attribute__((address_space(1))) unsigned int*)(const void*)g,
      (__attribute__((address_space(3))) unsigned int*)(void*)l, 16, 0, 0);
}
__device__ __forceinline__ bf16x8 pack8(const float4* br, int c) {
  union { bf16x8 v; unsigned u[4]; } p;
  p.u[0] = cvtpk((&br[0].x)[c], (&br[1].x)[c]);
  p.u[1] = cvtpk((&br[2].x)[c], (&br[3].x)[c]);
  p.u[2] = cvtpk((&br[4].x)[c], (&br[5].x)[c]);
  p.u[3] = cvtpk((&br[6].x)[c], (&br[7].x)[c]);
  return p.v;
}

// ---------------- router ----------------
__global__ void router_kernel(const float* __restrict__ x, const float* __restrict__ Wr,
                              int* __restrict__ cnt, int* __restrict__ tok,
                              float* __restrict__ prb) {
  int t = (blockIdx.x * blockDim.x + threadIdx.x) >> 6;
  int lane = threadIdx.x & 63;
  if (t >= T_TOK) return;
  const float* xr = x + (size_t)t * DDIM;
  float acc[NEXP];
#pragma unroll
  for (int e = 0; e < NEXP; ++e) acc[e] = 0.f;
#pragma unroll
  for (int i = 0; i < 4; ++i) {
    int d0 = lane * 16 + i * 4;
    float4 xv = *reinterpret_cast<const float4*>(xr + d0);
#pragma unroll
    for (int j = 0; j < 4; ++j) {
      float xd = (&xv.x)[j];
      float4 w0 = *reinterpret_cast<const float4*>(Wr + (size_t)(d0 + j) * NEXP);
      float4 w1 = *reinterpret_cast<const float4*>(Wr + (size_t)(d0 + j) * NEXP + 4);
      acc[0] += xd * w0.x; acc[1] += xd * w0.y; acc[2] += xd * w0.z; acc[3] += xd * w0.w;
      acc[4] += xd * w1.x; acc[5] += xd * w1.y; acc[6] += xd * w1.z; acc[7] += xd * w1.w;
    }
  }
#pragma unroll
  for (int off = 32; off >= 1; off >>= 1)
#pragma unroll
    for (int e = 0; e < NEXP; ++e) acc[e] += __shfl_down(acc[e], off);
  if (lane == 0) {
    float v0 = -1e30f, v1 = -1e30f; int i0 = 0, i1 = 0;
#pragma unroll
    for (int e = 0; e < NEXP; ++e) {
      float v = acc[e];
      if (v > v0)      { v1 = v0; i1 = i0; v0 = v; i0 = e; }
      else if (v > v1) { v1 = v; i1 = e; }
    }
    float e1 = __expf(v1 - v0);
    float p0 = 1.f / (1.f + e1);
    float p1 = e1 * p0;
    int s0 = atomicAdd(&cnt[i0], 1);
    tok[i0 * T_TOK + s0] = t; prb[i0 * T_TOK + s0] = p0;
    int s1 = atomicAdd(&cnt[i1], 1);
    tok[i1 * T_TOK + s1] = t; prb[i1 * T_TOK + s1] = p1;
  }
}

// ---------------- gather+cvt: xg[off_e + s] = bf16(x[tok[e][s]]) ------------
__global__ void gather_x_kernel(const float* __restrict__ x, const int* __restrict__ cnt,
                                const int* __restrict__ tok, unsigned short* __restrict__ xg) {
  int gs = blockIdx.x * 4 + (threadIdx.x >> 6);   // global slot [0, 4096)
  int lane = threadIdx.x & 63;
  int s = gs, e = 0;
#pragma unroll
  for (int i = 0; i < NEXP - 1; ++i) {
    int c = cnt[i];
    bool go = (e == i) && (s >= c);
    if (go) { s -= c; e = i + 1; }
  }
  int tk = tok[e * T_TOK + s];
  const float* src = x + (size_t)tk * DDIM;
  unsigned short* dst = xg + (size_t)gs * DDIM;
#pragma unroll
  for (int it = 0; it < 4; ++it) {
    float4 v = *reinterpret_cast<const float4*>(src + it * 256 + lane * 4);
    uint2 p;
    p.x = cvtpk(v.x, v.y);
    p.y = cvtpk(v.z, v.w);
    *reinterpret_cast<uint2*>(dst + it * 256 + lane * 4) = p;
  }
}

// ======== fused GEMM1: act = silu(xg@W1) * (xg@W3), 32x32x16 MFMA ========
// Block 256m x 64n(dual), 4 waves m-stacked, wave 64m x 64n h+g.
// Per K-step(64): 4 kk x {a[2]+b1[2]+b3[2] reads, 8 MFMA} = 42.7 FLOP/LDS-byte.
__global__ __launch_bounds__(256, 2)
void gemm1ab_kernel(const unsigned short* __restrict__ xg,
                    const float* __restrict__ W1, const float* __restrict__ W3,
                    const int* __restrict__ cnt,
                    unsigned short* __restrict__ act) {
  const int e = blockIdx.z;
  const int cn = cnt[e];
  const int r0 = blockIdx.y * 256;
  if (r0 >= cn) return;
  const int n0 = blockIdx.x * 64;
  int off = 0;
#pragma unroll
  for (int i = 0; i < NEXP; ++i) off += (i < e) ? cnt[i] : 0;

  __shared__ __align__(16) unsigned short sA[256 * 64];      // 32 KB
  __shared__ __align__(16) unsigned short sB1[64 * 64];      // 8 KB
  __shared__ __align__(16) unsigned short sB3[64 * 64];      // 8 KB

  const int tid = threadIdx.x;
  const int lane = tid & 63;
  const int wid = tid >> 6;

  // A staging: 8 gl16/thread covering 256 rows (pre-swizzled source, R16 pattern)
  const unsigned short* asrc[8];
#pragma unroll
  for (int i = 0; i < 8; ++i) {
    int row = (wid * 8 + i) * 8 + (lane >> 3);
    int sl = (lane & 7) ^ (row & 7);
    asrc[i] = xg + (size_t)(off + r0 + row) * DDIM + sl * 8;
  }

  // B staging: tid<128 stages W1, tid>=128 stages W3; thread owns 8k x 4n (R14).
  const int lt = tid & 127;
  const int ko = lt >> 4;
  const int nc = (lt & 15) * 4;
  const float* bp = ((tid < 128) ? W1 : W3) + ((size_t)e * DDIM + 8 * ko) * FDIM + n0 + nc;
  unsigned short* wb = (tid < 128) ? sB1 : sB3;
  int woff[4];
#pragma unroll
  for (int c = 0; c < 4; ++c) woff[c] = (nc + c) * 64 + ((ko ^ SBW(nc + c)) * 8);

  float4 br[8];
#define LOADB1(K0)                                                              \
  _Pragma("unroll") for (int r = 0; r < 8; ++r)                                 \
      br[r] = *reinterpret_cast<const float4*>(bp + (size_t)((K0) + r) * FDIM);
#define WRITEB1()                                                               \
  _Pragma("unroll") for (int c = 0; c < 4; ++c)                                 \
      *reinterpret_cast<bf16x8*>(wb + woff[c]) = pack8(br, c);
#define STAGEA1(K0)                                                             \
  _Pragma("unroll") for (int i = 0; i < 8; ++i)                                 \
      gl16(asrc[i] + (K0), &sA[(wid * 8 + i) * 512]);

  f32x16 ah[2][2], ag[2][2];
#pragma unroll
  for (int m = 0; m < 2; ++m)
#pragma unroll
    for (int n = 0; n < 2; ++n) {
      ah[m][n] = (f32x16)(0.f);
      ag[m][n] = (f32x16)(0.f);
    }

  LOADB1(0);

  const int l31 = lane & 31;
  const int khalf = lane >> 5;    // 0..1

  for (int k0 = 0; k0 < DDIM; k0 += 64) {
    WRITEB1();
    STAGEA1(k0);
    __syncthreads();
    if (k0 + 64 < DDIM) LOADB1(k0 + 64);
#pragma unroll
    for (int kk = 0; kk < 4; ++kk) {
      int s = kk * 2 + khalf;      // b128 slot 0..7
      bf16x8 a[2], b1[2], b3[2];
#pragma unroll
      for (int m = 0; m < 2; ++m) {
        int row = wid * 64 + m * 32 + l31;
        a[m] = *reinterpret_cast<const bf16x8*>(&sA[row * 64 + ((s ^ (row & 7)) * 8)]);
      }
#pragma unroll
      for (int n = 0; n < 2; ++n) {
        int rowb = n * 32 + l31;
        int offb = rowb * 64 + ((s ^ SBW(rowb)) * 8);
        b1[n] = *reinterpret_cast<const bf16x8*>(&sB1[offb]);
        b3[n] = *reinterpret_cast<const bf16x8*>(&sB3[offb]);
      }
#pragma unroll
      for (int m = 0; m < 2; ++m)
#pragma unroll
        for (int n = 0; n < 2; ++n) {
          ah[m][n] = __builtin_amdgcn_mfma_f32_32x32x16_bf16(a[m], b1[n], ah[m][n], 0, 0, 0);
          ag[m][n] = __builtin_amdgcn_mfma_f32_32x32x16_bf16(a[m], b3[n], ag[m][n], 0, 0, 0);
        }
    }
    __syncthreads();
  }

  // epilogue: act = silu(h) * g ; C/D map: col=lane&31, row=(r&3)+8*(r>>2)+4*(lane>>5)
#pragma unroll
  for (int m = 0; m < 2; ++m)
#pragma unroll
    for (int r = 0; r < 16; ++r) {
      int rloc = wid * 64 + m * 32 + (r & 3) + 8 * (r >> 2) + 4 * khalf;
      int s = r0 + rloc;
      if (s < cn) {
        unsigned short* orow = act + (size_t)(off + s) * FDIM + n0 + l31;
#pragma unroll
        for (int n = 0; n < 2; ++n) {
          float hv = ah[m][n][r];
          float gv = ag[m][n][r];
          float sg = hv / (1.f + __expf(-hv));
          orow[n * 32] = f2b(sg * gv);
        }
      }
    }
}

// ======== GEMM2: out += p * act @ W2 (split-K=2, atomics), 32x32x16 ========
// Block 256m x 128n, 4 waves m-stacked, wave 64m x 128n, acc[2][4].
__global__ __launch_bounds__(256, 2)
void gemm2d_kernel(const unsigned short* __restrict__ act, const float* __restrict__ W2,
                   const int* __restrict__ cnt, const int* __restrict__ tok,
                   const float* __restrict__ prb, float* __restrict__ out) {
  const int e = blockIdx.z >> 1;
  const int sp = blockIdx.z & 1;
  const int cn = cnt[e];
  const int r0 = blockIdx.y * 256;
  if (r0 >= cn) return;
  const int n0 = blockIdx.x * 128;
  const int kbase = sp * (FDIM / 2);
  int off = 0;
#pragma unroll
  for (int i = 0; i < NEXP; ++i) off += (i < e) ? cnt[i] : 0;

  __shared__ __align__(16) unsigned short sA[256 * 64];      // 32 KB
  __shared__ __align__(16) unsigned short sB[128 * 64];      // 16 KB

  const int tid = threadIdx.x;
  const int lane = tid & 63;
  const int wid = tid >> 6;

  const unsigned short* asrc[8];
#pragma unroll
  for (int i = 0; i < 8; ++i) {
    int row = (wid * 8 + i) * 8 + (lane >> 3);
    int sl = (lane & 7) ^ (row & 7);
    asrc[i] = act + (size_t)(off + r0 + row) * FDIM + kbase + sl * 8;
  }

  const int ko = tid >> 5;          // 0..7
  const int nc = (tid & 31) * 4;    // 0..124
  const float* bp = W2 + ((size_t)e * FDIM + kbase + 8 * ko) * DDIM + n0 + nc;
  int woff[4];
#pragma unroll
  for (int c = 0; c < 4; ++c) woff[c] = (nc + c) * 64 + ((ko ^ SBW(nc + c)) * 8);

  float4 br[8];
#define LOADB2(K0)                                                              \
  _Pragma("unroll") for (int r = 0; r < 8; ++r)                                 \
      br[r] = *reinterpret_cast<const float4*>(bp + (size_t)((K0) + r) * DDIM);
#define WRITEB2()                                                               \
  _Pragma("unroll") for (int c = 0; c < 4; ++c)                                 \
      *reinterpret_cast<bf16x8*>(&sB[woff[c]]) = pack8(br, c);
#define STAGEA2(K0)                                                             \
  _Pragma("unroll") for (int i = 0; i < 8; ++i)                                 \
      gl16(asrc[i] + (K0), &sA[(wid * 8 + i) * 512]);

  f32x16 acc[2][4];
#pragma unroll
  for (int m = 0; m < 2; ++m)
#pragma unroll
    for (int n = 0; n < 4; ++n) acc[m][n] = (f32x16)(0.f);

  LOADB2(0);

  const int l31 = lane & 31;
  const int khalf = lane >> 5;

  for (int k0 = 0; k0 < FDIM / 2; k0 += 64) {
    WRITEB2();
    STAGEA2(k0);
    __syncthreads();
    if (k0 + 64 < FDIM / 2) LOADB2(k0 + 64);
#pragma unroll
    for (int kk = 0; kk < 4; ++kk) {
      int s = kk * 2 + khalf;
      bf16x8 a[2], b[4];
#pragma unroll
      for (int m = 0; m < 2; ++m) {
        int row = wid * 64 + m * 32 + l31;
        a[m] = *reinterpret_cast<const bf16x8*>(&sA[row * 64 + ((s ^ (row & 7)) * 8)]);
      }
#pragma unroll
      for (int n = 0; n < 4; ++n) {
        int col = n * 32 + l31;
        b[n] = *reinterpret_cast<const bf16x8*>(&sB[col * 64 + ((s ^ SBW(col)) * 8)]);
      }
#pragma unroll
      for (int m = 0; m < 2; ++m)
#pragma unroll
        for (int n = 0; n < 4; ++n)
          acc[m][n] = __builtin_amdgcn_mfma_f32_32x32x16_bf16(a[m], b[n], acc[m][n], 0, 0, 0);
    }
    __syncthreads();
  }

#pragma unroll
  for (int m = 0; m < 2; ++m)
#pragma unroll
    for (int r = 0; r < 16; ++r) {
      int rloc = wid * 64 + m * 32 + (r & 3) + 8 * (r >> 2) + 4 * khalf;
      int s = r0 + rloc;
      if (s < cn) {
        int tkn = tok[e * T_TOK + s];
        float p = prb[e * T_TOK + s];
        float* orow = out + (size_t)tkn * DDIM + n0 + l31;
#pragma unroll
        for (int n = 0; n < 4; ++n) atomicAdd(&orow[n * 32], p * acc[m][n][r]);
      }
    }
}

// ============================================================================
extern "C" void kernel_launch(void* const* d_in, const int* in_sizes, int n_in,
                              void* d_out, int out_size, void* d_ws, size_t ws_size,
                              hipStream_t stream) {
  const float* x  = (const float*)d_in[0];
  const float* Wr = (const float*)d_in[1];
  const float* W1 = (const float*)d_in[2];
  const float* W2 = (const float*)d_in[3];
  const float* W3 = (const float*)d_in[4];
  float* out = (float*)d_out;

  char* ws = (char*)d_ws;
  int*   cnt = (int*)ws;                      // 32 B
  int*   tok = (int*)(ws + 1024);             // 64 KB
  float* prb = (float*)(ws + 1024 + 65536);   // 64 KB
  unsigned short* xg  = (unsigned short*)(ws + 256 * 1024);   // ROWS x DDIM bf16
  unsigned short* act = xg + (size_t)ROWS * DDIM;             // ROWS x FDIM bf16

  hipMemsetAsync(cnt, 0, NEXP * sizeof(int), stream);
  hipMemsetAsync(d_out, 0, (size_t)out_size * sizeof(float), stream);

  router_kernel<<<T_TOK / 4, 256, 0, stream>>>(x, Wr, cnt, tok, prb);
  gather_x_kernel<<<(2 * T_TOK) / 4, 256, 0, stream>>>(x, cnt, tok, xg);
  gemm1ab_kernel<<<dim3(FDIM / 64, 8, NEXP), 256, 0, stream>>>(xg, W1, W3, cnt, act);
  gemm2d_kernel<<<dim3(DDIM / 128, 8, NEXP * 2), 256, 0, stream>>>(act, W2, cnt, tok, prb, out);
}

// Round 18
// 290.546 us; speedup vs baseline: 2.3147x; 1.0424x over previous
//
#include <hip/hip_runtime.h>
#include <hip/hip_bf16.h>

#define T_TOK 2048
#define DDIM  1024
#define NEXP  8
#define FDIM  4096
#define ROWS  (4096 + 256)

typedef __attribute__((ext_vector_type(8))) short bf16x8;
typedef __attribute__((ext_vector_type(4))) float f32x4;

#define SBW(n) ((((n) >> 3) ^ (n)) & 7)

__device__ __forceinline__ unsigned short f2b(float f) {
  union { float f; unsigned u; } v; v.f = f;
  unsigned r = v.u + 0x7FFF + ((v.u >> 16) & 1);  // RNE
  return (unsigned short)(r >> 16);
}
__device__ __forceinline__ float b2f(unsigned short s) {
  union { unsigned u; float f; } v; v.u = ((unsigned)s) << 16;
  return v.f;
}
__device__ __forceinline__ unsigned cvtpk(float lo, float hi) {
  unsigned r;
  asm("v_cvt_pk_bf16_f32 %0, %1, %2" : "=v"(r) : "v"(lo), "v"(hi));
  return r;
}
__device__ __forceinline__ void gl16(const unsigned short* g, unsigned short* l) {
  __builtin_amdgcn_global_load_lds(
      (const __attribute__((address_space(1))) unsigned int*)(const void*)g,
      (__attribute__((address_space(3))) unsigned int*)(void*)l, 16, 0, 0);
}
__device__ __forceinline__ bf16x8 pack8(const float4* br, int c) {
  union { bf16x8 v; unsigned u[4]; } p;
  p.u[0] = cvtpk((&br[0].x)[c], (&br[1].x)[c]);
  p.u[1] = cvtpk((&br[2].x)[c], (&br[3].x)[c]);
  p.u[2] = cvtpk((&br[4].x)[c], (&br[5].x)[c]);
  p.u[3] = cvtpk((&br[6].x)[c], (&br[7].x)[c]);
  return p.v;
}

// ---------------- router (also records each token's two global slots) -------
__global__ void router_kernel(const float* __restrict__ x, const float* __restrict__ Wr,
                              int* __restrict__ cnt, int* __restrict__ tok,
                              float* __restrict__ prb, int* __restrict__ tsl) {
  int t = (blockIdx.x * blockDim.x + threadIdx.x) >> 6;
  int lane = threadIdx.x & 63;
  if (t >= T_TOK) return;
  const float* xr = x + (size_t)t * DDIM;
  float acc[NEXP];
#pragma unroll
  for (int e = 0; e < NEXP; ++e) acc[e] = 0.f;
#pragma unroll
  for (int i = 0; i < 4; ++i) {
    int d0 = lane * 16 + i * 4;
    float4 xv = *reinterpret_cast<const float4*>(xr + d0);
#pragma unroll
    for (int j = 0; j < 4; ++j) {
      float xd = (&xv.x)[j];
      float4 w0 = *reinterpret_cast<const float4*>(Wr + (size_t)(d0 + j) * NEXP);
      float4 w1 = *reinterpret_cast<const float4*>(Wr + (size_t)(d0 + j) * NEXP + 4);
      acc[0] += xd * w0.x; acc[1] += xd * w0.y; acc[2] += xd * w0.z; acc[3] += xd * w0.w;
      acc[4] += xd * w1.x; acc[5] += xd * w1.y; acc[6] += xd * w1.z; acc[7] += xd * w1.w;
    }
  }
#pragma unroll
  for (int off = 32; off >= 1; off >>= 1)
#pragma unroll
    for (int e = 0; e < NEXP; ++e) acc[e] += __shfl_down(acc[e], off);
  if (lane == 0) {
    float v0 = -1e30f, v1 = -1e30f; int i0 = 0, i1 = 0;
#pragma unroll
    for (int e = 0; e < NEXP; ++e) {
      float v = acc[e];
      if (v > v0)      { v1 = v0; i1 = i0; v0 = v; i0 = e; }
      else if (v > v1) { v1 = v; i1 = e; }
    }
    float e1 = __expf(v1 - v0);
    float p0 = 1.f / (1.f + e1);
    float p1 = e1 * p0;
    int s0 = atomicAdd(&cnt[i0], 1);
    tok[i0 * T_TOK + s0] = t; prb[i0 * T_TOK + s0] = p0;
    int s1 = atomicAdd(&cnt[i1], 1);
    tok[i1 * T_TOK + s1] = t; prb[i1 * T_TOK + s1] = p1;
    tsl[t * 2]     = i0 * T_TOK + s0;
    tsl[t * 2 + 1] = i1 * T_TOK + s1;
  }
}

// ---------------- gather+cvt: xg[off_e + s] = bf16(x[tok[e][s]]) ------------
__global__ void gather_x_kernel(const float* __restrict__ x, const int* __restrict__ cnt,
                                const int* __restrict__ tok, unsigned short* __restrict__ xg) {
  int gs = blockIdx.x * 4 + (threadIdx.x >> 6);   // global slot [0, 4096)
  int lane = threadIdx.x & 63;
  int s = gs, e = 0;
#pragma unroll
  for (int i = 0; i < NEXP - 1; ++i) {
    int c = cnt[i];
    bool go = (e == i) && (s >= c);
    if (go) { s -= c; e = i + 1; }
  }
  int tk = tok[e * T_TOK + s];
  const float* src = x + (size_t)tk * DDIM;
  unsigned short* dst = xg + (size_t)gs * DDIM;
#pragma unroll
  for (int it = 0; it < 4; ++it) {
    float4 v = *reinterpret_cast<const float4*>(src + it * 256 + lane * 4);
    uint2 p;
    p.x = cvtpk(v.x, v.y);
    p.y = cvtpk(v.z, v.w);
    *reinterpret_cast<uint2*>(dst + it * 256 + lane * 4) = p;
  }
}

// ======== fused GEMM1: act = silu(xg@W1) * (xg@W3) [R14 champion, verbatim] ==
__global__ __launch_bounds__(256, 3)
void gemm1ab_kernel(const unsigned short* __restrict__ xg,
                    const float* __restrict__ W1, const float* __restrict__ W3,
                    const int* __restrict__ cnt,
                    unsigned short* __restrict__ act) {
  const int e = blockIdx.z;
  const int cn = cnt[e];
  const int r0 = blockIdx.y * 128;
  if (r0 >= cn) return;
  const int n0 = blockIdx.x * 64;
  int off = 0;
#pragma unroll
  for (int i = 0; i < NEXP; ++i) off += (i < e) ? cnt[i] : 0;

  __shared__ __align__(16) unsigned short sA[128 * 64];      // 16 KB
  __shared__ __align__(16) unsigned short sB1[64 * 64];      // 8 KB
  __shared__ __align__(16) unsigned short sB3[64 * 64];      // 8 KB

  const int tid = threadIdx.x;
  const int lane = tid & 63;
  const int wid = tid >> 6;
  const int wm = wid >> 1, wn = wid & 1;

  const unsigned short* asrc[4];
#pragma unroll
  for (int i = 0; i < 4; ++i) {
    int row = (4 * wid + i) * 8 + (lane >> 3);
    int sl = (lane & 7) ^ (row & 7);
    asrc[i] = xg + (size_t)(off + r0 + row) * DDIM + sl * 8;
  }

  const int lt = tid & 127;
  const int ko = lt >> 4;
  const int nc = (lt & 15) * 4;
  const float* bp = ((tid < 128) ? W1 : W3) + ((size_t)e * DDIM + 8 * ko) * FDIM + n0 + nc;
  unsigned short* wb = (tid < 128) ? sB1 : sB3;
  int woff[4];
#pragma unroll
  for (int c = 0; c < 4; ++c) woff[c] = (nc + c) * 64 + ((ko ^ SBW(nc + c)) * 8);

  float4 br[8];
#define LOADB1(K0)                                                              \
  _Pragma("unroll") for (int r = 0; r < 8; ++r)                                 \
      br[r] = *reinterpret_cast<const float4*>(bp + (size_t)((K0) + r) * FDIM);
#define WRITEB1()                                                               \
  _Pragma("unroll") for (int c = 0; c < 4; ++c)                                 \
      *reinterpret_cast<bf16x8*>(wb + woff[c]) = pack8(br, c);
#define STAGEA1(K0)                                                             \
  _Pragma("unroll") for (int i = 0; i < 4; ++i)                                 \
      gl16(asrc[i] + (K0), &sA[(4 * wid + i) * 512]);

  f32x4 ah[4][2], ag[4][2];
#pragma unroll
  for (int m = 0; m < 4; ++m)
#pragma unroll
    for (int n = 0; n < 2; ++n) { ah[m][n] = (f32x4){0,0,0,0}; ag[m][n] = (f32x4){0,0,0,0}; }

  LOADB1(0);

  for (int k0 = 0; k0 < DDIM; k0 += 64) {
    WRITEB1();
    STAGEA1(k0);
    __syncthreads();
    if (k0 + 64 < DDIM) LOADB1(k0 + 64);
#pragma unroll
    for (int kk = 0; kk < 2; ++kk) {
      int kc8 = kk * 4 + (lane >> 4);
      bf16x8 a[4], b1[2], b3[2];
#pragma unroll
      for (int m = 0; m < 4; ++m) {
        int row = wm * 64 + m * 16 + (lane & 15);
        a[m] = *reinterpret_cast<const bf16x8*>(&sA[row * 64 + ((kc8 ^ (row & 7)) * 8)]);
      }
#pragma unroll
      for (int n = 0; n < 2; ++n) {
        int rowb = wn * 32 + n * 16 + (lane & 15);
        int offb = rowb * 64 + ((kc8 ^ SBW(rowb)) * 8);
        b1[n] = *reinterpret_cast<const bf16x8*>(&sB1[offb]);
        b3[n] = *reinterpret_cast<const bf16x8*>(&sB3[offb]);
      }
#pragma unroll
      for (int m = 0; m < 4; ++m)
#pragma unroll
        for (int n = 0; n < 2; ++n) {
          ah[m][n] = __builtin_amdgcn_mfma_f32_16x16x32_bf16(a[m], b1[n], ah[m][n], 0, 0, 0);
          ag[m][n] = __builtin_amdgcn_mfma_f32_16x16x32_bf16(a[m], b3[n], ag[m][n], 0, 0, 0);
        }
    }
    __syncthreads();
  }
#pragma unroll
  for (int m = 0; m < 4; ++m)
#pragma unroll
    for (int j = 0; j < 4; ++j) {
      int rloc = wm * 64 + m * 16 + (lane >> 4) * 4 + j;
      int s = r0 + rloc;
      if (s < cn) {
        unsigned short* orow = act + (size_t)(off + s) * FDIM + n0 + wn * 32 + (lane & 15);
#pragma unroll
        for (int n = 0; n < 2; ++n) {
          float hv = ah[m][n][j];
          float gv = ag[m][n][j];
          float sg = hv / (1.f + __expf(-hv));
          orow[n * 16] = f2b(sg * gv);
        }
      }
    }
}

// ======== GEMM2p: y[sp] = act @ W2 (split-K=2, PLAIN STORES, no atomics) =====
// R14 gemm2d body; epilogue stores raw partials to y0/y1; combine applies p.
__global__ __launch_bounds__(256, 3)
void gemm2p_kernel(const unsigned short* __restrict__ act, const float* __restrict__ W2,
                   const int* __restrict__ cnt,
                   float* __restrict__ y0, float* __restrict__ y1) {
  const int e = blockIdx.z >> 1;
  const int sp = blockIdx.z & 1;
  const int cn = cnt[e];
  const int r0 = blockIdx.y * 128;
  if (r0 >= cn) return;
  const int n0 = blockIdx.x * 128;
  const int kbase = sp * (FDIM / 2);
  int off = 0;
#pragma unroll
  for (int i = 0; i < NEXP; ++i) off += (i < e) ? cnt[i] : 0;

  __shared__ __align__(16) unsigned short sA[128 * 64];      // 16 KB
  __shared__ __align__(16) unsigned short sB[128 * 64];      // 16 KB

  const int tid = threadIdx.x;
  const int lane = tid & 63;
  const int wid = tid >> 6;
  const int wm = wid >> 1, wn = wid & 1;

  const unsigned short* asrc[4];
#pragma unroll
  for (int i = 0; i < 4; ++i) {
    int row = (4 * wid + i) * 8 + (lane >> 3);
    int sl = (lane & 7) ^ (row & 7);
    asrc[i] = act + (size_t)(off + r0 + row) * FDIM + kbase + sl * 8;
  }

  const int ko = tid >> 5;          // 0..7
  const int nc = (tid & 31) * 4;    // 0..124
  const float* bp = W2 + ((size_t)e * FDIM + kbase + 8 * ko) * DDIM + n0 + nc;
  int woff[4];
#pragma unroll
  for (int c = 0; c < 4; ++c) woff[c] = (nc + c) * 64 + ((ko ^ SBW(nc + c)) * 8);

  float4 br[8];
#define LOADB2(K0)                                                              \
  _Pragma("unroll") for (int r = 0; r < 8; ++r)                                 \
      br[r] = *reinterpret_cast<const float4*>(bp + (size_t)((K0) + r) * DDIM);
#define WRITEB2()                                                               \
  _Pragma("unroll") for (int c = 0; c < 4; ++c)                                 \
      *reinterpret_cast<bf16x8*>(&sB[woff[c]]) = pack8(br, c);
#define STAGEA2(K0)                                                             \
  _Pragma("unroll") for (int i = 0; i < 4; ++i)                                 \
      gl16(asrc[i] + (K0), &sA[(4 * wid + i) * 512]);

  f32x4 acc[4][4];
#pragma unroll
  for (int m = 0; m < 4; ++m)
#pragma unroll
    for (int n = 0; n < 4; ++n) acc[m][n] = (f32x4){0,0,0,0};

  LOADB2(0);

  for (int k0 = 0; k0 < FDIM / 2; k0 += 64) {
    WRITEB2();
    STAGEA2(k0);
    __syncthreads();
    if (k0 + 64 < FDIM / 2) LOADB2(k0 + 64);
#pragma unroll
    for (int kk = 0; kk < 2; ++kk) {
      int kc8 = kk * 4 + (lane >> 4);
      bf16x8 a[4], b[4];
#pragma unroll
      for (int m = 0; m < 4; ++m) {
        int row = wm * 64 + m * 16 + (lane & 15);
        a[m] = *reinterpret_cast<const bf16x8*>(&sA[row * 64 + ((kc8 ^ (row & 7)) * 8)]);
      }
#pragma unroll
      for (int n = 0; n < 4; ++n) {
        int col = wn * 64 + n * 16 + (lane & 15);
        b[n] = *reinterpret_cast<const bf16x8*>(&sB[col * 64 + ((kc8 ^ SBW(col)) * 8)]);
      }
#pragma unroll
      for (int m = 0; m < 4; ++m)
#pragma unroll
        for (int n = 0; n < 4; ++n)
          acc[m][n] = __builtin_amdgcn_mfma_f32_16x16x32_bf16(a[m], b[n], acc[m][n], 0, 0, 0);
    }
    __syncthreads();
  }
  float* yb = (sp ? y1 : y0);
#pragma unroll
  for (int m = 0; m < 4; ++m)
#pragma unroll
    for (int j = 0; j < 4; ++j) {
      int rloc = wm * 64 + m * 16 + (lane >> 4) * 4 + j;
      int s = r0 + rloc;
      if (s < cn) {
        float* orow = yb + (size_t)(off + s) * DDIM + n0 + wn * 64 + (lane & 15);
#pragma unroll
        for (int n = 0; n < 4; ++n) orow[n * 16] = acc[m][n][j];
      }
    }
}

// ---------------- combine: out[t] = p0*(y0+y1)[g0] + p1*(y0+y1)[g1] ---------
__global__ void combine_kernel(const float* __restrict__ y0, const float* __restrict__ y1,
                               const int* __restrict__ cnt, const int* __restrict__ tsl,
                               const float* __restrict__ prb, float* __restrict__ out) {
  const int t = blockIdx.x;
  int pre[NEXP];
  pre[0] = 0;
#pragma unroll
  for (int i = 1; i < NEXP; ++i) pre[i] = pre[i - 1] + cnt[i - 1];
  int a = tsl[t * 2], b = tsl[t * 2 + 1];
  int ea = a >> 11, sa = a & (T_TOK - 1);
  int eb = b >> 11, sb = b & (T_TOK - 1);
  size_t ga = (size_t)(pre[ea] + sa) * DDIM;
  size_t gb = (size_t)(pre[eb] + sb) * DDIM;
  float pa = prb[a], pb = prb[b];
  int c = threadIdx.x * 4;
  float4 a0 = *reinterpret_cast<const float4*>(y0 + ga + c);
  float4 a1 = *reinterpret_cast<const float4*>(y1 + ga + c);
  float4 b0 = *reinterpret_cast<const float4*>(y0 + gb + c);
  float4 b1 = *reinterpret_cast<const float4*>(y1 + gb + c);
  float4 o;
  o.x = pa * (a0.x + a1.x) + pb * (b0.x + b1.x);
  o.y = pa * (a0.y + a1.y) + pb * (b0.y + b1.y);
  o.z = pa * (a0.z + a1.z) + pb * (b0.z + b1.z);
  o.w = pa * (a0.w + a1.w) + pb * (b0.w + b1.w);
  *reinterpret_cast<float4*>(out + (size_t)t * DDIM + c) = o;
}

// ============================================================================
extern "C" void kernel_launch(void* const* d_in, const int* in_sizes, int n_in,
                              void* d_out, int out_size, void* d_ws, size_t ws_size,
                              hipStream_t stream) {
  const float* x  = (const float*)d_in[0];
  const float* Wr = (const float*)d_in[1];
  const float* W1 = (const float*)d_in[2];
  const float* W2 = (const float*)d_in[3];
  const float* W3 = (const float*)d_in[4];
  float* out = (float*)d_out;

  char* ws = (char*)d_ws;
  int*   cnt = (int*)ws;                      // 32 B
  int*   tok = (int*)(ws + 1024);             // 64 KB
  float* prb = (float*)(ws + 1024 + 65536);   // 64 KB
  int*   tsl = (int*)(ws + 1024 + 2 * 65536); // 16 KB
  unsigned short* xg  = (unsigned short*)(ws + 256 * 1024);   // ROWS x DDIM bf16 (~8.9 MB)
  unsigned short* act = xg + (size_t)ROWS * DDIM;             // ROWS x FDIM bf16 (~35.6 MB)
  float* y0 = (float*)(act + (size_t)ROWS * FDIM);            // ROWS x DDIM f32 (~17.8 MB)
  float* y1 = y0 + (size_t)ROWS * DDIM;                       // ROWS x DDIM f32

  hipMemsetAsync(cnt, 0, NEXP * sizeof(int), stream);

  router_kernel<<<T_TOK / 4, 256, 0, stream>>>(x, Wr, cnt, tok, prb, tsl);
  gather_x_kernel<<<(2 * T_TOK) / 4, 256, 0, stream>>>(x, cnt, tok, xg);
  gemm1ab_kernel<<<dim3(FDIM / 64, 16, NEXP), 256, 0, stream>>>(xg, W1, W3, cnt, act);
  gemm2p_kernel<<<dim3(DDIM / 128, 16, NEXP * 2), 256, 0, stream>>>(act, W2, cnt, y0, y1);
  combine_kernel<<<T_TOK, 256, 0, stream>>>(y0, y1, cnt, tsl, prb, out);
}